// Round 12
// baseline (341.594 us; speedup 1.0000x reference)
//
#include <hip/hip_runtime.h>
#include <stdint.h>

#define NB 4096
#define NT 200
#define NE 64
// attention: 4E=256 -> 64 -> 32 -> 1 ; final MLP: 272 -> 256 -> 128 -> 1
//
// ABI (proven R2-R10): identity order, fp32 floats, int32 ints, FP32 output.
//
// R25: R24 + in-register interest + epilogue prefetch.
//  - R24 post-mortem: MFMA path works (192us, MfmaUtil 8%, VALU 25%,
//    absmax 1.2e-7). Now latency-bound: FETCH +75MB and a 50-iter
//    dependent-gather tail = the fp32 interest re-gather; occupancy
//    ~2.9 waves/SIMD can't hide it.
//  - Interest from the bf16 hi/lo key fragments ALREADY in registers
//    (hi+lo ~ fp32 to 2^-18 rel): per-lane weighted sum over its 4 rows
//    x 16 cols, reduce across the 16 l15-lanes (DPP xor1/xor2 +
//    shfl_xor 4/8), 16 b32 LDS writes per wave. Re-gather deleted.
//  - Epilogue user/ctx/dense rows prefetched into registers at start
//    (no dependent loads after the last barrier).
//  - din_mlp: unchanged (MR=4, transposed LDS, unroll-8).

typedef __attribute__((ext_vector_type(8))) __bf16 bf16x8;
typedef __attribute__((ext_vector_type(4))) float f32x4;

__device__ __forceinline__ void cvt8(const float4 a, const float4 b,
                                     bf16x8& hi, bf16x8& lo)
{
    float x[8] = {a.x, a.y, a.z, a.w, b.x, b.y, b.z, b.w};
#pragma unroll
    for (int i = 0; i < 8; ++i) {
        const __bf16 h = (__bf16)x[i];
        hi[i] = h;
        lo[i] = (__bf16)(x[i] - (float)h);
    }
}

// quad-perm DPP helpers (VALU pipe)
__device__ __forceinline__ float dpp_xor1(float x)   // [1,0,3,2]
{
    return __int_as_float(__builtin_amdgcn_update_dpp(
        0, __float_as_int(x), 0xB1, 0xF, 0xF, true));
}
__device__ __forceinline__ float dpp_xor2(float x)   // [2,3,0,1]
{
    return __int_as_float(__builtin_amdgcn_update_dpp(
        0, __float_as_int(x), 0x4E, 0xF, 0xF, true));
}

struct __align__(16) SmemM {
    __bf16 wT_hi[64 * 72];    // WeffT[j][k], pitch 72 (144B, b128-aligned)
    __bf16 wT_lo[64 * 72];
    __bf16 w2T_hi[32 * 72];   // w2T[o][j]
    __bf16 w2T_lo[32 * 72];
    float  q[64];
    float  biasj[64];
    float  b2[32];
    float  wo[32];
    float  ip[4 * 64];        // bias partials, later interest partials
    float  red_a[4];
    float  red_b[4];
    float  scores[256];
    float  bounce[4][16 * 36];  // per-wave transpose buffer (pitch 36 dw)
};                               // ~39.7 KB -> 4 blocks/CU by LDS

__global__ __launch_bounds__(256)
void din_attn(const int* __restrict__ target_item,
              const int* __restrict__ history_items,
              const int* __restrict__ history_mask,
              const int* __restrict__ sparse_features,
              const float* __restrict__ dense_features,
              const float* __restrict__ item_table,
              const float* __restrict__ user_table,
              const float* __restrict__ ctx_table,
              const float* __restrict__ att_w1,
              const float* __restrict__ att_b1,
              const float* __restrict__ att_w2,
              const float* __restrict__ att_b2,
              const float* __restrict__ att_wo,
              const float* __restrict__ att_bo,
              float* __restrict__ mlp_in)   // [NB][272]
{
    __shared__ SmemM sm;

    const int b    = blockIdx.x;
    const int tid  = threadIdx.x;    // 0..255
    const int wv   = tid >> 6;       // wave 0..3
    const int lane = tid & 63;
    const int l15  = lane & 15;
    const int g4   = lane >> 4;      // 0..3

    // ---- A-fragments: gather own key rows, split to bf16 hi/lo ----------
    // A[row][k]: row = 64*wv + mt*16 + (lane&15), k = ks*32 + (lane>>4)*8+i
    bf16x8 khi[4][2], klo[4][2];
#pragma unroll
    for (int mt = 0; mt < 4; ++mt) {
        int t = 64 * wv + mt * 16 + l15;
        if (t > NT - 1) t = NT - 1;                 // dead rows: masked later
        const int hr = history_items[(size_t)b * NT + t];
        const float* kp = item_table + (size_t)hr * NE + g4 * 8;
#pragma unroll
        for (int ks = 0; ks < 2; ++ks) {
            const float4 f0 = *(const float4*)(kp + ks * 32);
            const float4 f1 = *(const float4*)(kp + ks * 32 + 4);
            cvt8(f0, f1, khi[mt][ks], klo[mt][ks]);
        }
    }

    // ---- epilogue prefetch (independent loads, hide under everything) ---
    float pre_u = 0.f, pre_c = 0.f, pre_d = 0.f;
    if (tid < NE) {
        pre_u = user_table[(size_t)sparse_features[b * 2 + 0] * NE + tid];
        pre_c = ctx_table[(size_t)sparse_features[b * 2 + 1] * NE + tid];
    } else if (tid < 80) {
        pre_d = dense_features[(size_t)b * 16 + (tid - 64)];
    }

    // ---- stage q, b2, wo -------------------------------------------------
    if (tid < NE) sm.q[tid] = item_table[(size_t)target_item[b] * NE + tid];
    if (tid < 32) { sm.b2[tid] = att_b2[tid]; sm.wo[tid] = att_wo[tid]; }
    const float bo = att_bo[0];
    __syncthreads();

    // ---- Weff^T split staging + bias partials ---------------------------
    // h1[j] = relu( sum_e k_e*(A+C+q_e*D)[e][j] + b1[j] + sum_e q_e*(B-C)[e][j] )
    {
        const int j = tid & 63;
        float pb = 0.f;
        for (int e = wv; e < NE; e += 4) {
            const float qe = sm.q[e];
            const float A  = att_w1[(size_t)(e)       * NE + j];
            const float Bv = att_w1[(size_t)(64 + e)  * NE + j];
            const float C  = att_w1[(size_t)(128 + e) * NE + j];
            const float D  = att_w1[(size_t)(192 + e) * NE + j];
            const float wf = A + C + qe * D;
            const __bf16 hi = (__bf16)wf;
            sm.wT_hi[j * 72 + e] = hi;
            sm.wT_lo[j * 72 + e] = (__bf16)(wf - (float)hi);
            pb += qe * (Bv - C);
        }
        sm.ip[wv * 64 + j] = pb;
    }
    // w2T[o][j] split staging (32x64, 8 elems/thread)
    {
        const int o  = tid & 31;
        const int jb = (tid >> 5) * 8;
#pragma unroll
        for (int i = 0; i < 8; ++i) {
            const int j = jb + i;
            const float v = att_w2[(size_t)j * 32 + o];
            const __bf16 hi = (__bf16)v;
            sm.w2T_hi[o * 72 + j] = hi;
            sm.w2T_lo[o * 72 + j] = (__bf16)(v - (float)hi);
        }
    }
    __syncthreads();
    if (tid < NE)
        sm.biasj[tid] = att_b1[tid] + sm.ip[tid] + sm.ip[64 + tid] +
                        sm.ip[128 + tid] + sm.ip[192 + tid];
    __syncthreads();

    // ---- L1 GEMM: h1[256x64] = K[256x64] . Weff[64x64]  (split, 96 MFMA) -
    f32x4 acc1[4][4];
    {
        const f32x4 z = {0.f, 0.f, 0.f, 0.f};
#pragma unroll
        for (int mt = 0; mt < 4; ++mt)
#pragma unroll
            for (int nt = 0; nt < 4; ++nt) acc1[mt][nt] = z;
    }
#pragma unroll
    for (int nt = 0; nt < 4; ++nt) {
        const __bf16* bph = sm.wT_hi + (nt * 16 + l15) * 72 + g4 * 8;
        const __bf16* bpl = sm.wT_lo + (nt * 16 + l15) * 72 + g4 * 8;
        const bf16x8 bh0 = *(const bf16x8*)(bph);
        const bf16x8 bh1 = *(const bf16x8*)(bph + 32);
        const bf16x8 bl0 = *(const bf16x8*)(bpl);
        const bf16x8 bl1 = *(const bf16x8*)(bpl + 32);
#pragma unroll
        for (int mt = 0; mt < 4; ++mt) {
            f32x4 a = acc1[mt][nt];
            a = __builtin_amdgcn_mfma_f32_16x16x32_bf16(khi[mt][0], bh0, a, 0, 0, 0);
            a = __builtin_amdgcn_mfma_f32_16x16x32_bf16(khi[mt][0], bl0, a, 0, 0, 0);
            a = __builtin_amdgcn_mfma_f32_16x16x32_bf16(klo[mt][0], bh0, a, 0, 0, 0);
            a = __builtin_amdgcn_mfma_f32_16x16x32_bf16(khi[mt][1], bh1, a, 0, 0, 0);
            a = __builtin_amdgcn_mfma_f32_16x16x32_bf16(khi[mt][1], bl1, a, 0, 0, 0);
            a = __builtin_amdgcn_mfma_f32_16x16x32_bf16(klo[mt][1], bh1, a, 0, 0, 0);
            acc1[mt][nt] = a;
        }
    }

    // ---- bias + ReLU on C1 (col = nt*16+l15, row = mt*16+g4*4+r) --------
#pragma unroll
    for (int nt = 0; nt < 4; ++nt) {
        const float bj = sm.biasj[nt * 16 + l15];
#pragma unroll
        for (int mt = 0; mt < 4; ++mt)
#pragma unroll
            for (int r = 0; r < 4; ++r)
                acc1[mt][nt][r] = fmaxf(acc1[mt][nt][r] + bj, 0.f);
    }

    // ---- transpose C1-layout -> A2-fragments via wave-private bounce ----
    bf16x8 a2hi[4][2], a2lo[4][2];
    {
        float* bnc = sm.bounce[wv];
#pragma unroll
        for (int mt = 0; mt < 4; ++mt) {
#pragma unroll
            for (int k2s = 0; k2s < 2; ++k2s) {
#pragma unroll
                for (int ntl = 0; ntl < 2; ++ntl) {
                    const int nt = k2s * 2 + ntl;
#pragma unroll
                    for (int r = 0; r < 4; ++r)
                        bnc[(g4 * 4 + r) * 36 + ntl * 16 + l15] = acc1[mt][nt][r];
                }
                // same-wave DS ops are ordered; compiler inserts lgkm waits
                const float* rp = bnc + l15 * 36 + g4 * 8;
                const float4 u0 = *(const float4*)(rp);
                const float4 u1 = *(const float4*)(rp + 4);
                cvt8(u0, u1, a2hi[mt][k2s], a2lo[mt][k2s]);
            }
        }
    }

    // ---- L2 GEMM: h2[256x32] = h1 . W2 (split, 48 MFMA) -----------------
    f32x4 acc2[4][2];
    {
        const f32x4 z = {0.f, 0.f, 0.f, 0.f};
#pragma unroll
        for (int mt = 0; mt < 4; ++mt) { acc2[mt][0] = z; acc2[mt][1] = z; }
    }
#pragma unroll
    for (int nt2 = 0; nt2 < 2; ++nt2) {
        const __bf16* bph = sm.w2T_hi + (nt2 * 16 + l15) * 72 + g4 * 8;
        const __bf16* bpl = sm.w2T_lo + (nt2 * 16 + l15) * 72 + g4 * 8;
        const bf16x8 bh0 = *(const bf16x8*)(bph);
        const bf16x8 bh1 = *(const bf16x8*)(bph + 32);
        const bf16x8 bl0 = *(const bf16x8*)(bpl);
        const bf16x8 bl1 = *(const bf16x8*)(bpl + 32);
#pragma unroll
        for (int mt = 0; mt < 4; ++mt) {
            f32x4 a = acc2[mt][nt2];
            a = __builtin_amdgcn_mfma_f32_16x16x32_bf16(a2hi[mt][0], bh0, a, 0, 0, 0);
            a = __builtin_amdgcn_mfma_f32_16x16x32_bf16(a2hi[mt][0], bl0, a, 0, 0, 0);
            a = __builtin_amdgcn_mfma_f32_16x16x32_bf16(a2lo[mt][0], bh0, a, 0, 0, 0);
            a = __builtin_amdgcn_mfma_f32_16x16x32_bf16(a2hi[mt][1], bh1, a, 0, 0, 0);
            a = __builtin_amdgcn_mfma_f32_16x16x32_bf16(a2hi[mt][1], bl1, a, 0, 0, 0);
            a = __builtin_amdgcn_mfma_f32_16x16x32_bf16(a2lo[mt][1], bh1, a, 0, 0, 0);
            acc2[mt][nt2] = a;
        }
    }

    // ---- L3 scores: relu(h2+b2).wo, reduce over the 16 col-lanes --------
    float sc[4][4];
#pragma unroll
    for (int mt = 0; mt < 4; ++mt)
#pragma unroll
        for (int r = 0; r < 4; ++r) sc[mt][r] = 0.f;
#pragma unroll
    for (int nt2 = 0; nt2 < 2; ++nt2) {
        const float bb = sm.b2[nt2 * 16 + l15];
        const float ww = sm.wo[nt2 * 16 + l15];
#pragma unroll
        for (int mt = 0; mt < 4; ++mt)
#pragma unroll
            for (int r = 0; r < 4; ++r)
                sc[mt][r] += fmaxf(acc2[mt][nt2][r] + bb, 0.f) * ww;
    }
#pragma unroll
    for (int mt = 0; mt < 4; ++mt)
#pragma unroll
        for (int r = 0; r < 4; ++r) {
            float v = sc[mt][r];
            v += __shfl_xor(v, 1);
            v += __shfl_xor(v, 2);
            v += __shfl_xor(v, 4);
            v += __shfl_xor(v, 8);
            sc[mt][r] = v;
        }
    if (l15 == 0) {
#pragma unroll
        for (int mt = 0; mt < 4; ++mt)
#pragma unroll
            for (int r = 0; r < 4; ++r) {
                const int t = 64 * wv + mt * 16 + g4 * 4 + r;
                float val;
                if (t < NT) {
                    const int mk = history_mask[(size_t)b * NT + t];
                    val = (mk != 0) ? (sc[mt][r] + bo) : -1e9f;
                } else {
                    val = -INFINITY;       // pad rows excluded from softmax
                }
                sm.scores[t] = val;
            }
    }
    __syncthreads();

    // ---- softmax over 256 slots (4-wave reduce) -------------------------
    const float v = sm.scores[tid];
    float m = v;
#pragma unroll
    for (int s = 32; s; s >>= 1) m = fmaxf(m, __shfl_xor(m, s));
    if (lane == 0) sm.red_a[wv] = m;
    __syncthreads();
    const float mx = fmaxf(fmaxf(sm.red_a[0], sm.red_a[1]),
                           fmaxf(sm.red_a[2], sm.red_a[3]));
    const float ex = __expf(v - mx);   // -inf -> 0
    float ssum = ex;
#pragma unroll
    for (int s = 32; s; s >>= 1) ssum += __shfl_xor(ssum, s);
    if (lane == 0) sm.red_b[wv] = ssum;
    __syncthreads();
    const float total = sm.red_b[0] + sm.red_b[1] + sm.red_b[2] + sm.red_b[3];
    sm.scores[tid] = ex / total;       // softmax weight of slot tid
    __syncthreads();

    // ---- interest from IN-REGISTER keys (no re-gather) ------------------
    // lane holds K[t(mt,l15)][e] for e = ks*32 + g4*8 + i as hi+lo.
    {
        float wt[4];
#pragma unroll
        for (int mt = 0; mt < 4; ++mt)
            wt[mt] = sm.scores[64 * wv + mt * 16 + l15];   // pad rows: 0

        float p0[8], p1[8];
#pragma unroll
        for (int i = 0; i < 8; ++i) { p0[i] = 0.f; p1[i] = 0.f; }
#pragma unroll
        for (int mt = 0; mt < 4; ++mt) {
#pragma unroll
            for (int i = 0; i < 8; ++i) {
                const float k0 = (float)khi[mt][0][i] + (float)klo[mt][0][i];
                const float k1 = (float)khi[mt][1][i] + (float)klo[mt][1][i];
                p0[i] += wt[mt] * k0;
                p1[i] += wt[mt] * k1;
            }
        }
        // reduce across the 16 l15-lanes (lane bits 0-3)
#pragma unroll
        for (int i = 0; i < 8; ++i) {
            float a = p0[i];
            a += dpp_xor1(a); a += dpp_xor2(a);
            a += __shfl_xor(a, 4); a += __shfl_xor(a, 8);
            p0[i] = a;
            float c = p1[i];
            c += dpp_xor1(c); c += dpp_xor2(c);
            c += __shfl_xor(c, 4); c += __shfl_xor(c, 8);
            p1[i] = c;
        }
        if (l15 == 0) {
#pragma unroll
            for (int i = 0; i < 8; ++i) {
                sm.ip[wv * 64 + g4 * 8 + i]      = p0[i];
                sm.ip[wv * 64 + 32 + g4 * 8 + i] = p1[i];
            }
        }
    }
    __syncthreads();

    // ---- assemble mlp_in row [user, ctx, q, interest, dense] ------------
    float* row = mlp_in + (size_t)b * 272;
    if (tid < NE) {
        const float inter = sm.ip[tid] + sm.ip[64 + tid] +
                            sm.ip[128 + tid] + sm.ip[192 + tid];
        row[0 + tid]   = pre_u;
        row[64 + tid]  = pre_c;
        row[128 + tid] = sm.q[tid];
        row[192 + tid] = inter;
    } else if (tid >= 64 && tid < 80) {
        row[256 + (tid - 64)] = pre_d;
    }
}

// ---------------------------------------------------------------------------
// Kernel 2: final MLP 272 -> 256 -> 128 -> 1, 4 rows/block (grid 1024,
// 4 blocks/CU) with transposed LDS activations (broadcast b128 reads) and
// unroll-8 load pipelining.  (unchanged)
// ---------------------------------------------------------------------------
#define MR 4
__global__ __launch_bounds__(256)
void din_mlp(const float* __restrict__ mlp_in,
             const float* __restrict__ w1,
             const float* __restrict__ b1,
             const float* __restrict__ w2,
             const float* __restrict__ b2,
             const float* __restrict__ ow,
             const float* __restrict__ ob,
             float* __restrict__ out)
{
    __shared__ float inT[272 * MR];     // [k][r]
    __shared__ float h1T[256 * MR];     // [k][r]
    __shared__ float p2[2 * MR * 128];
    __shared__ float h2_lds[MR * 128];

    const int b0  = blockIdx.x * MR;
    const int tid = threadIdx.x;

    // stage transposed: coalesced global read, scattered LDS write
    for (int i = tid; i < MR * 272; i += 256) {
        const int r = i / 272, k = i - 272 * r;
        inT[k * MR + r] = mlp_in[(size_t)b0 * 272 + i];
    }
    __syncthreads();

    // layer 1: 272 -> 256 (thread = col, MR rows via 1 b128 broadcast/k)
    {
        const float bias = b1[tid];
        float a0 = bias, a1 = bias, a2 = bias, a3 = bias;
        const float4* iT = (const float4*)inT;
#pragma unroll 8
        for (int k = 0; k < 272; ++k) {
            const float wv = w1[(size_t)k * 256 + tid];
            const float4 iv = iT[k];
            a0 += iv.x * wv; a1 += iv.y * wv;
            a2 += iv.z * wv; a3 += iv.w * wv;
        }
        float4 o;
        o.x = fmaxf(a0, 0.f); o.y = fmaxf(a1, 0.f);
        o.z = fmaxf(a2, 0.f); o.w = fmaxf(a3, 0.f);
        ((float4*)h1T)[tid] = o;        // h1T[k=tid][r] contiguous
    }
    __syncthreads();

    // layer 2: 256 -> 128, split-K over two half-blocks
    {
        const int o = tid & 127, half = tid >> 7;
        float c0 = 0.f, c1 = 0.f, c2 = 0.f, c3 = 0.f;
        const float4* hT = (const float4*)h1T;
#pragma unroll 8
        for (int kk = 0; kk < 128; ++kk) {
            const int k = half * 128 + kk;
            const float wv = w2[(size_t)k * 128 + o];
            const float4 hv = hT[k];
            c0 += hv.x * wv; c1 += hv.y * wv;
            c2 += hv.z * wv; c3 += hv.w * wv;
        }
        p2[(half * MR + 0) * 128 + o] = c0;
        p2[(half * MR + 1) * 128 + o] = c1;
        p2[(half * MR + 2) * 128 + o] = c2;
        p2[(half * MR + 3) * 128 + o] = c3;
    }
    __syncthreads();
    if (tid < 128) {
        const float bias = b2[tid];
#pragma unroll
        for (int r = 0; r < MR; ++r)
            h2_lds[r * 128 + tid] =
                fmaxf(p2[r * 128 + tid] + p2[(MR + r) * 128 + tid] + bias, 0.f);
    }
    __syncthreads();

    // layer 3: 128 -> 1 (16 lanes per row)
    if (tid < 16 * MR) {
        const int r = tid >> 4, l = tid & 15;
        float a = 0.f;
#pragma unroll
        for (int kk = 0; kk < 8; ++kk) {
            const int k = l * 8 + kk;
            a += h2_lds[r * 128 + k] * ow[k];
        }
        a += __shfl_xor(a, 8, 16);
        a += __shfl_xor(a, 4, 16);
        a += __shfl_xor(a, 2, 16);
        a += __shfl_xor(a, 1, 16);
        if (l == 0) out[b0 + r] = a + ob[0];
    }
}

// ---------------------------------------------------------------------------
extern "C" void kernel_launch(void* const* d_in, const int* in_sizes, int n_in,
                              void* d_out, int out_size, void* d_ws, size_t ws_size,
                              hipStream_t stream)
{
    float* mlp_in = (float*)d_ws;   // 4096*272*4 = 4.46 MB

    din_attn<<<NB, 256, 0, stream>>>(
        (const int*)d_in[0],      // target_item
        (const int*)d_in[1],      // history_items
        (const int*)d_in[2],      // history_mask
        (const int*)d_in[3],      // sparse_features
        (const float*)d_in[4],    // dense_features
        (const float*)d_in[5],    // item_table
        (const float*)d_in[6],    // user_table
        (const float*)d_in[7],    // ctx_table
        (const float*)d_in[8],  (const float*)d_in[9],   // att_w1, att_b1
        (const float*)d_in[10], (const float*)d_in[11],  // att_w2, att_b2
        (const float*)d_in[12], (const float*)d_in[13],  // att_wo, att_bo
        mlp_in);

    din_mlp<<<NB / MR, 256, 0, stream>>>(
        mlp_in,
        (const float*)d_in[14], (const float*)d_in[15],  // mlp_w1, mlp_b1
        (const float*)d_in[16], (const float*)d_in[17],  // mlp_w2, mlp_b2
        (const float*)d_in[18], (const float*)d_in[19],  // out_w, out_b
        (float*)d_out);
}

// Round 13
// 257.180 us; speedup vs baseline: 1.3282x; 1.3282x over previous
//
#include <hip/hip_runtime.h>
#include <stdint.h>

#define NB 4096
#define NT 200
#define NE 64
// attention: 4E=256 -> 64 -> 32 -> 1 ; final MLP: 272 -> 256 -> 128 -> 1
//
// ABI (proven R2-R10): identity order, fp32 floats, int32 ints, FP32 output.
//
// R26: 8-wave attn (halve per-wave critical path) + MR=2 mlp (8 blk/CU).
//  - R24 (best attn, 192us): latency-bound (VALU 25%, MFMA 8%, HBM 11%)
//    at 2.9 waves/SIMD; per-wave serial chain = 96 MFMA + 8 bounce
//    phases + 16-load gather + 50-iter interest.
//  - R25 post-mortem: in-register interest kept keys live through
//    softmax -> VGPR 140, occ 11%, 219us. Reverted to fp32 re-gather
//    (also restores absmax 1.2e-7).
//  - Now: 512 threads, 8 waves, wave owns 2 row-tiles (mt=0..1): state
//    ~110 total/wave (~4 w/SIMD), all serial phases halve. weffT staged
//    as ONE b128 store/thread (8 consecutive e) vs 32 ds_write_b16.
//    LDS ~50KB -> 3 blocks/CU (24 waves ceiling, regs bind ~4/SIMD).
//  - din_mlp: MR=2, grid 2048 = 8 blocks/CU (full 32 waves/CU), unroll
//    16; weight re-read ~830MB L2 ~= 25us BW, latency-win dominates.

typedef __attribute__((ext_vector_type(8))) __bf16 bf16x8;
typedef __attribute__((ext_vector_type(4))) __bf16 bf16x4;
typedef __attribute__((ext_vector_type(4))) float f32x4;

__device__ __forceinline__ void cvt8(const float4 a, const float4 b,
                                     bf16x8& hi, bf16x8& lo)
{
    float x[8] = {a.x, a.y, a.z, a.w, b.x, b.y, b.z, b.w};
#pragma unroll
    for (int i = 0; i < 8; ++i) {
        const __bf16 h = (__bf16)x[i];
        hi[i] = h;
        lo[i] = (__bf16)(x[i] - (float)h);
    }
}

struct __align__(16) SmemM {
    __bf16 wT_hi[64 * 72];    // WeffT[j][k], pitch 72 (144B, b128-aligned)
    __bf16 wT_lo[64 * 72];
    __bf16 w2T_hi[32 * 72];   // w2T[o][j]
    __bf16 w2T_lo[32 * 72];
    float  q[64];
    float  biasj[64];
    float  b2[32];
    float  wo[32];
    float  ip[8 * 64];        // bias partials, later interest partials
    float  red_a[8];
    float  red_b[8];
    float  scores[256];
    float  bounce[8][16 * 36];  // per-wave transpose buffer (pitch 36 dw)
};                               // ~50.0 KB -> 3 blocks/CU

__global__ __launch_bounds__(512)
void din_attn(const int* __restrict__ target_item,
              const int* __restrict__ history_items,
              const int* __restrict__ history_mask,
              const int* __restrict__ sparse_features,
              const float* __restrict__ dense_features,
              const float* __restrict__ item_table,
              const float* __restrict__ user_table,
              const float* __restrict__ ctx_table,
              const float* __restrict__ att_w1,
              const float* __restrict__ att_b1,
              const float* __restrict__ att_w2,
              const float* __restrict__ att_b2,
              const float* __restrict__ att_wo,
              const float* __restrict__ att_bo,
              float* __restrict__ mlp_in)   // [NB][272]
{
    __shared__ SmemM sm;

    const int b    = blockIdx.x;
    const int tid  = threadIdx.x;    // 0..511
    const int wv   = tid >> 6;       // wave 0..7
    const int lane = tid & 63;
    const int l15  = lane & 15;
    const int g4   = lane >> 4;      // 0..3

    // ---- A-fragments: wave owns rows 32*wv + mt*16 + l15, mt=0..1 -------
    // A[row][k]: k = ks*32 + g4*8 + i
    bf16x8 khi[2][2], klo[2][2];
#pragma unroll
    for (int mt = 0; mt < 2; ++mt) {
        int t = 32 * wv + mt * 16 + l15;
        if (t > NT - 1) t = NT - 1;                 // dead rows: masked later
        const int hr = history_items[(size_t)b * NT + t];
        const float* kp = item_table + (size_t)hr * NE + g4 * 8;
#pragma unroll
        for (int ks = 0; ks < 2; ++ks) {
            const float4 f0 = *(const float4*)(kp + ks * 32);
            const float4 f1 = *(const float4*)(kp + ks * 32 + 4);
            cvt8(f0, f1, khi[mt][ks], klo[mt][ks]);
        }
    }

    // ---- epilogue prefetch (independent loads; 3 VGPRs) -----------------
    float pre_u = 0.f, pre_c = 0.f, pre_d = 0.f;
    if (tid < NE) {
        pre_u = user_table[(size_t)sparse_features[b * 2 + 0] * NE + tid];
        pre_c = ctx_table[(size_t)sparse_features[b * 2 + 1] * NE + tid];
    } else if (tid < 80) {
        pre_d = dense_features[(size_t)b * 16 + (tid - 64)];
    }

    // ---- stage q, b2, wo -------------------------------------------------
    if (tid < NE) sm.q[tid] = item_table[(size_t)target_item[b] * NE + tid];
    if (tid < 32) { sm.b2[tid] = att_b2[tid]; sm.wo[tid] = att_wo[tid]; }
    const float bo = att_bo[0];
    __syncthreads();

    // ---- Weff^T split staging (1 b128 store/thread) + bias partials -----
    // h1[j] = relu( sum_e k_e*(A+C+q_e*D)[e][j] + b1[j] + sum_e q_e*(B-C)[e][j] )
    {
        const int j  = tid & 63;
        const int eb = (tid >> 6) * 8;   // 8 consecutive e per thread
        float pb = 0.f;
        bf16x8 vhi, vlo;
#pragma unroll
        for (int i = 0; i < 8; ++i) {
            const int e = eb + i;
            const float qe = sm.q[e];
            const float A  = att_w1[(size_t)(e)       * NE + j];
            const float Bv = att_w1[(size_t)(64 + e)  * NE + j];
            const float C  = att_w1[(size_t)(128 + e) * NE + j];
            const float D  = att_w1[(size_t)(192 + e) * NE + j];
            const float wf = A + C + qe * D;
            const __bf16 h = (__bf16)wf;
            vhi[i] = h;
            vlo[i] = (__bf16)(wf - (float)h);
            pb += qe * (Bv - C);
        }
        *(bf16x8*)(sm.wT_hi + (size_t)j * 72 + eb) = vhi;
        *(bf16x8*)(sm.wT_lo + (size_t)j * 72 + eb) = vlo;
        sm.ip[(tid >> 6) * 64 + j] = pb;
    }
    // w2T[o][j] split staging (b64 stores, 4 j per thread)
    {
        const int o  = tid & 31;
        const int jb = (tid >> 5) * 4;   // 0..60
        bf16x4 vhi, vlo;
#pragma unroll
        for (int i = 0; i < 4; ++i) {
            const float v = att_w2[(size_t)(jb + i) * 32 + o];
            const __bf16 h = (__bf16)v;
            vhi[i] = h;
            vlo[i] = (__bf16)(v - (float)h);
        }
        *(bf16x4*)(sm.w2T_hi + (size_t)o * 72 + jb) = vhi;
        *(bf16x4*)(sm.w2T_lo + (size_t)o * 72 + jb) = vlo;
    }
    __syncthreads();
    if (tid < NE) {
        float s = att_b1[tid];
#pragma unroll
        for (int w = 0; w < 8; ++w) s += sm.ip[w * 64 + tid];
        sm.biasj[tid] = s;
    }
    __syncthreads();

    // ---- L1 GEMM: h1 = K . Weff  (split-3, 48 MFMA/wave) ----------------
    f32x4 acc1[2][4];
    {
        const f32x4 z = {0.f, 0.f, 0.f, 0.f};
#pragma unroll
        for (int mt = 0; mt < 2; ++mt)
#pragma unroll
            for (int nt = 0; nt < 4; ++nt) acc1[mt][nt] = z;
    }
#pragma unroll
    for (int nt = 0; nt < 4; ++nt) {
        const __bf16* bph = sm.wT_hi + (nt * 16 + l15) * 72 + g4 * 8;
        const __bf16* bpl = sm.wT_lo + (nt * 16 + l15) * 72 + g4 * 8;
        const bf16x8 bh0 = *(const bf16x8*)(bph);
        const bf16x8 bh1 = *(const bf16x8*)(bph + 32);
        const bf16x8 bl0 = *(const bf16x8*)(bpl);
        const bf16x8 bl1 = *(const bf16x8*)(bpl + 32);
#pragma unroll
        for (int mt = 0; mt < 2; ++mt) {
            f32x4 a = acc1[mt][nt];
            a = __builtin_amdgcn_mfma_f32_16x16x32_bf16(khi[mt][0], bh0, a, 0, 0, 0);
            a = __builtin_amdgcn_mfma_f32_16x16x32_bf16(khi[mt][0], bl0, a, 0, 0, 0);
            a = __builtin_amdgcn_mfma_f32_16x16x32_bf16(klo[mt][0], bh0, a, 0, 0, 0);
            a = __builtin_amdgcn_mfma_f32_16x16x32_bf16(khi[mt][1], bh1, a, 0, 0, 0);
            a = __builtin_amdgcn_mfma_f32_16x16x32_bf16(khi[mt][1], bl1, a, 0, 0, 0);
            a = __builtin_amdgcn_mfma_f32_16x16x32_bf16(klo[mt][1], bh1, a, 0, 0, 0);
            acc1[mt][nt] = a;
        }
    }

    // ---- bias + ReLU on C1 (col = nt*16+l15, row-in-tile = g4*4+r) ------
#pragma unroll
    for (int nt = 0; nt < 4; ++nt) {
        const float bj = sm.biasj[nt * 16 + l15];
#pragma unroll
        for (int mt = 0; mt < 2; ++mt)
#pragma unroll
            for (int r = 0; r < 4; ++r)
                acc1[mt][nt][r] = fmaxf(acc1[mt][nt][r] + bj, 0.f);
    }

    // ---- transpose C1-layout -> A2-fragments via wave-private bounce ----
    bf16x8 a2hi[2][2], a2lo[2][2];
    {
        float* bnc = sm.bounce[wv];
#pragma unroll
        for (int mt = 0; mt < 2; ++mt) {
#pragma unroll
            for (int k2s = 0; k2s < 2; ++k2s) {
#pragma unroll
                for (int ntl = 0; ntl < 2; ++ntl) {
                    const int nt = k2s * 2 + ntl;
#pragma unroll
                    for (int r = 0; r < 4; ++r)
                        bnc[(g4 * 4 + r) * 36 + ntl * 16 + l15] = acc1[mt][nt][r];
                }
                // same-wave DS ops are ordered; compiler inserts lgkm waits
                const float* rp = bnc + l15 * 36 + g4 * 8;
                const float4 u0 = *(const float4*)(rp);
                const float4 u1 = *(const float4*)(rp + 4);
                cvt8(u0, u1, a2hi[mt][k2s], a2lo[mt][k2s]);
            }
        }
    }

    // ---- L2 GEMM: h2 = h1 . W2 (split-3, 24 MFMA/wave) ------------------
    f32x4 acc2[2][2];
    {
        const f32x4 z = {0.f, 0.f, 0.f, 0.f};
#pragma unroll
        for (int mt = 0; mt < 2; ++mt) { acc2[mt][0] = z; acc2[mt][1] = z; }
    }
#pragma unroll
    for (int nt2 = 0; nt2 < 2; ++nt2) {
        const __bf16* bph = sm.w2T_hi + (nt2 * 16 + l15) * 72 + g4 * 8;
        const __bf16* bpl = sm.w2T_lo + (nt2 * 16 + l15) * 72 + g4 * 8;
        const bf16x8 bh0 = *(const bf16x8*)(bph);
        const bf16x8 bh1 = *(const bf16x8*)(bph + 32);
        const bf16x8 bl0 = *(const bf16x8*)(bpl);
        const bf16x8 bl1 = *(const bf16x8*)(bpl + 32);
#pragma unroll
        for (int mt = 0; mt < 2; ++mt) {
            f32x4 a = acc2[mt][nt2];
            a = __builtin_amdgcn_mfma_f32_16x16x32_bf16(a2hi[mt][0], bh0, a, 0, 0, 0);
            a = __builtin_amdgcn_mfma_f32_16x16x32_bf16(a2hi[mt][0], bl0, a, 0, 0, 0);
            a = __builtin_amdgcn_mfma_f32_16x16x32_bf16(a2lo[mt][0], bh0, a, 0, 0, 0);
            a = __builtin_amdgcn_mfma_f32_16x16x32_bf16(a2hi[mt][1], bh1, a, 0, 0, 0);
            a = __builtin_amdgcn_mfma_f32_16x16x32_bf16(a2hi[mt][1], bl1, a, 0, 0, 0);
            a = __builtin_amdgcn_mfma_f32_16x16x32_bf16(a2lo[mt][1], bh1, a, 0, 0, 0);
            acc2[mt][nt2] = a;
        }
    }

    // ---- L3 scores: relu(h2+b2).wo, reduce over the 16 col-lanes --------
    float sc[2][4];
#pragma unroll
    for (int mt = 0; mt < 2; ++mt)
#pragma unroll
        for (int r = 0; r < 4; ++r) sc[mt][r] = 0.f;
#pragma unroll
    for (int nt2 = 0; nt2 < 2; ++nt2) {
        const float bb = sm.b2[nt2 * 16 + l15];
        const float ww = sm.wo[nt2 * 16 + l15];
#pragma unroll
        for (int mt = 0; mt < 2; ++mt)
#pragma unroll
            for (int r = 0; r < 4; ++r)
                sc[mt][r] += fmaxf(acc2[mt][nt2][r] + bb, 0.f) * ww;
    }
#pragma unroll
    for (int mt = 0; mt < 2; ++mt)
#pragma unroll
        for (int r = 0; r < 4; ++r) {
            float v = sc[mt][r];
            v += __shfl_xor(v, 1);
            v += __shfl_xor(v, 2);
            v += __shfl_xor(v, 4);
            v += __shfl_xor(v, 8);
            sc[mt][r] = v;
        }
    if (l15 == 0) {
#pragma unroll
        for (int mt = 0; mt < 2; ++mt)
#pragma unroll
            for (int r = 0; r < 4; ++r) {
                const int t = 32 * wv + mt * 16 + g4 * 4 + r;
                float val;
                if (t < NT) {
                    const int mk = history_mask[(size_t)b * NT + t];
                    val = (mk != 0) ? (sc[mt][r] + bo) : -1e9f;
                } else {
                    val = -INFINITY;       // pad rows excluded from softmax
                }
                sm.scores[t] = val;
            }
    }
    __syncthreads();

    // ---- softmax over 256 slots (8-wave reduce; tid>=256 inert) ---------
    const float v = (tid < 256) ? sm.scores[tid] : -INFINITY;
    float m = v;
#pragma unroll
    for (int s = 32; s; s >>= 1) m = fmaxf(m, __shfl_xor(m, s));
    if (lane == 0) sm.red_a[wv] = m;
    __syncthreads();
    float mx = sm.red_a[0];
#pragma unroll
    for (int w = 1; w < 8; ++w) mx = fmaxf(mx, sm.red_a[w]);
    const float ex = __expf(v - mx);   // -inf -> 0
    float ssum = ex;
#pragma unroll
    for (int s = 32; s; s >>= 1) ssum += __shfl_xor(ssum, s);
    if (lane == 0) sm.red_b[wv] = ssum;
    __syncthreads();
    float total = 0.f;
#pragma unroll
    for (int w = 0; w < 8; ++w) total += sm.red_b[w];
    if (tid < 256) sm.scores[tid] = ex / total;   // softmax weight of slot
    __syncthreads();

    // ---- interest in FP32: re-gather K rows (L2/L3-hot), 25 t per wave --
    {
        const int e = lane;            // 0..63
        float acc = 0.f;
        const int tb = 25 * wv;        // 8 waves x 25 = 200 exactly
#pragma unroll 5
        for (int i = 0; i < 25; ++i) {
            const int t = tb + i;
            const float wt = sm.scores[t];
            const int hr = history_items[(size_t)b * NT + t];
            acc += wt * item_table[(size_t)hr * NE + e];
        }
        sm.ip[wv * 64 + e] = acc;
    }
    __syncthreads();

    // ---- assemble mlp_in row [user, ctx, q, interest, dense] ------------
    float* row = mlp_in + (size_t)b * 272;
    if (tid < NE) {
        float inter = 0.f;
#pragma unroll
        for (int w = 0; w < 8; ++w) inter += sm.ip[w * 64 + tid];
        row[0 + tid]   = pre_u;
        row[64 + tid]  = pre_c;
        row[128 + tid] = sm.q[tid];
        row[192 + tid] = inter;
    } else if (tid >= 64 && tid < 80) {
        row[256 + (tid - 64)] = pre_d;
    }
}

// ---------------------------------------------------------------------------
// Kernel 2: final MLP 272 -> 256 -> 128 -> 1, 2 rows/block (grid 2048,
// 8 blocks/CU = full occupancy) with transposed LDS activations and
// unroll-16 load pipelining.
// ---------------------------------------------------------------------------
#define MR 2
__global__ __launch_bounds__(256)
void din_mlp(const float* __restrict__ mlp_in,
             const float* __restrict__ w1,
             const float* __restrict__ b1,
             const float* __restrict__ w2,
             const float* __restrict__ b2,
             const float* __restrict__ ow,
             const float* __restrict__ ob,
             float* __restrict__ out)
{
    __shared__ float inT[272 * MR];     // [k][r]
    __shared__ float h1T[256 * MR];     // [k][r]
    __shared__ float p2[2 * MR * 128];
    __shared__ float h2_lds[MR * 128];

    const int b0  = blockIdx.x * MR;
    const int tid = threadIdx.x;

    // stage transposed: coalesced global read, scattered LDS write
    for (int i = tid; i < MR * 272; i += 256) {
        const int r = i / 272, k = i - 272 * r;
        inT[k * MR + r] = mlp_in[(size_t)b0 * 272 + i];
    }
    __syncthreads();

    // layer 1: 272 -> 256 (thread = col, MR rows via 1 b64 broadcast/k)
    {
        const float bias = b1[tid];
        float a0 = bias, a1 = bias;
        const float2* iT = (const float2*)inT;
#pragma unroll 16
        for (int k = 0; k < 272; ++k) {
            const float wv = w1[(size_t)k * 256 + tid];
            const float2 iv = iT[k];
            a0 += iv.x * wv; a1 += iv.y * wv;
        }
        float2 o;
        o.x = fmaxf(a0, 0.f); o.y = fmaxf(a1, 0.f);
        ((float2*)h1T)[tid] = o;        // h1T[k=tid][r] contiguous
    }
    __syncthreads();

    // layer 2: 256 -> 128, split-K over two half-blocks
    {
        const int o = tid & 127, half = tid >> 7;
        float c0 = 0.f, c1 = 0.f;
        const float2* hT = (const float2*)h1T;
#pragma unroll 16
        for (int kk = 0; kk < 128; ++kk) {
            const int k = half * 128 + kk;
            const float wv = w2[(size_t)k * 128 + o];
            const float2 hv = hT[k];
            c0 += hv.x * wv; c1 += hv.y * wv;
        }
        p2[(half * MR + 0) * 128 + o] = c0;
        p2[(half * MR + 1) * 128 + o] = c1;
    }
    __syncthreads();
    if (tid < 128) {
        const float bias = b2[tid];
#pragma unroll
        for (int r = 0; r < MR; ++r)
            h2_lds[r * 128 + tid] =
                fmaxf(p2[r * 128 + tid] + p2[(MR + r) * 128 + tid] + bias, 0.f);
    }
    __syncthreads();

    // layer 3: 128 -> 1 (16 lanes per row)
    if (tid < 16 * MR) {
        const int r = tid >> 4, l = tid & 15;
        float a = 0.f;
#pragma unroll
        for (int kk = 0; kk < 8; ++kk) {
            const int k = l * 8 + kk;
            a += h2_lds[r * 128 + k] * ow[k];
        }
        a += __shfl_xor(a, 8, 16);
        a += __shfl_xor(a, 4, 16);
        a += __shfl_xor(a, 2, 16);
        a += __shfl_xor(a, 1, 16);
        if (l == 0) out[b0 + r] = a + ob[0];
    }
}

// ---------------------------------------------------------------------------
extern "C" void kernel_launch(void* const* d_in, const int* in_sizes, int n_in,
                              void* d_out, int out_size, void* d_ws, size_t ws_size,
                              hipStream_t stream)
{
    float* mlp_in = (float*)d_ws;   // 4096*272*4 = 4.46 MB

    din_attn<<<NB, 512, 0, stream>>>(
        (const int*)d_in[0],      // target_item
        (const int*)d_in[1],      // history_items
        (const int*)d_in[2],      // history_mask
        (const int*)d_in[3],      // sparse_features
        (const float*)d_in[4],    // dense_features
        (const float*)d_in[5],    // item_table
        (const float*)d_in[6],    // user_table
        (const float*)d_in[7],    // ctx_table
        (const float*)d_in[8],  (const float*)d_in[9],   // att_w1, att_b1
        (const float*)d_in[10], (const float*)d_in[11],  // att_w2, att_b2
        (const float*)d_in[12], (const float*)d_in[13],  // att_wo, att_bo
        mlp_in);

    din_mlp<<<NB / MR, 256, 0, stream>>>(
        mlp_in,
        (const float*)d_in[14], (const float*)d_in[15],  // mlp_w1, mlp_b1
        (const float*)d_in[16], (const float*)d_in[17],  // mlp_w2, mlp_b2
        (const float*)d_in[18], (const float*)d_in[19],  // out_w, out_b
        (float*)d_out);
}

// Round 14
// 238.478 us; speedup vs baseline: 1.4324x; 1.0784x over previous
//
#include <hip/hip_runtime.h>
#include <stdint.h>

#define NB 4096
#define NT 200
#define NE 64
// attention: 4E=256 -> 64 -> 32 -> 1 ; final MLP: 272 -> 256 -> 128 -> 1
//
// ABI (proven R2-R10): identity order, fp32 floats, int32 ints, FP32 output.
//
// R27: MFMA din_mlp (fused 3-layer GEMM chain, split-3 bf16).
//  - R26 post-mortem: attn 122us (8-wave MFMA, occ 43%). By subtraction
//    din_mlp ~115-125us -- 5x above its ~24us L2-BW floor, stuck at
//    ~100-130us across MR=16/8/4/2 (scalar-VALU latency-bound,
//    MfmaUtil=0 on a 4096x272x256 GEMM).
//  - Now: block = 16 rows x 512 thr (8 waves), grid 256 (1/CU exact).
//    GEMM1 h1[16x256]=X[16x272(pad288)].W1 : wave covers 32 cols,
//    2nt x 9ks x 3 = 54 MFMA. GEMM2 h2[16x128]=h1.W2 : 16 cols/wave,
//    8ks x 3 = 24 MFMA. GEMM3 = shuffle-reduce dot with out_w.
//    Layouts copied from the PROVEN attn kernel: A row=l15 k=g4*8+i;
//    B via Wt[n][k] fragment reads (8 scalar global loads, L2-hot);
//    C/D col=l15 row=g4*4+r. X and h1 in LDS as bf16 hi/lo, pitch 296
//    (148 dw = 20 mod 32 -> 2-way banks, free). k>=272 guarded (W1 OOB)
//    and X zero-padded so the 9th K-step is exact.
//  - din_attn: unchanged from R26 (proven 122us, absmax 1.5e-8).

typedef __attribute__((ext_vector_type(8))) __bf16 bf16x8;
typedef __attribute__((ext_vector_type(4))) __bf16 bf16x4;
typedef __attribute__((ext_vector_type(4))) float f32x4;

__device__ __forceinline__ void cvt8(const float4 a, const float4 b,
                                     bf16x8& hi, bf16x8& lo)
{
    float x[8] = {a.x, a.y, a.z, a.w, b.x, b.y, b.z, b.w};
#pragma unroll
    for (int i = 0; i < 8; ++i) {
        const __bf16 h = (__bf16)x[i];
        hi[i] = h;
        lo[i] = (__bf16)(x[i] - (float)h);
    }
}

__device__ __forceinline__ void cvt8a(const float* x, bf16x8& hi, bf16x8& lo)
{
#pragma unroll
    for (int i = 0; i < 8; ++i) {
        const __bf16 h = (__bf16)x[i];
        hi[i] = h;
        lo[i] = (__bf16)(x[i] - (float)h);
    }
}

struct __align__(16) SmemM {
    __bf16 wT_hi[64 * 72];    // WeffT[j][k], pitch 72 (144B, b128-aligned)
    __bf16 wT_lo[64 * 72];
    __bf16 w2T_hi[32 * 72];   // w2T[o][j]
    __bf16 w2T_lo[32 * 72];
    float  q[64];
    float  biasj[64];
    float  b2[32];
    float  wo[32];
    float  ip[8 * 64];        // bias partials, later interest partials
    float  red_a[8];
    float  red_b[8];
    float  scores[256];
    float  bounce[8][16 * 36];  // per-wave transpose buffer (pitch 36 dw)
};                               // ~50.0 KB -> 3 blocks/CU

__global__ __launch_bounds__(512)
void din_attn(const int* __restrict__ target_item,
              const int* __restrict__ history_items,
              const int* __restrict__ history_mask,
              const int* __restrict__ sparse_features,
              const float* __restrict__ dense_features,
              const float* __restrict__ item_table,
              const float* __restrict__ user_table,
              const float* __restrict__ ctx_table,
              const float* __restrict__ att_w1,
              const float* __restrict__ att_b1,
              const float* __restrict__ att_w2,
              const float* __restrict__ att_b2,
              const float* __restrict__ att_wo,
              const float* __restrict__ att_bo,
              float* __restrict__ mlp_in)   // [NB][272]
{
    __shared__ SmemM sm;

    const int b    = blockIdx.x;
    const int tid  = threadIdx.x;    // 0..511
    const int wv   = tid >> 6;       // wave 0..7
    const int lane = tid & 63;
    const int l15  = lane & 15;
    const int g4   = lane >> 4;      // 0..3

    // ---- A-fragments: wave owns rows 32*wv + mt*16 + l15, mt=0..1 -------
    bf16x8 khi[2][2], klo[2][2];
#pragma unroll
    for (int mt = 0; mt < 2; ++mt) {
        int t = 32 * wv + mt * 16 + l15;
        if (t > NT - 1) t = NT - 1;                 // dead rows: masked later
        const int hr = history_items[(size_t)b * NT + t];
        const float* kp = item_table + (size_t)hr * NE + g4 * 8;
#pragma unroll
        for (int ks = 0; ks < 2; ++ks) {
            const float4 f0 = *(const float4*)(kp + ks * 32);
            const float4 f1 = *(const float4*)(kp + ks * 32 + 4);
            cvt8(f0, f1, khi[mt][ks], klo[mt][ks]);
        }
    }

    // ---- epilogue prefetch (independent loads; 3 VGPRs) -----------------
    float pre_u = 0.f, pre_c = 0.f, pre_d = 0.f;
    if (tid < NE) {
        pre_u = user_table[(size_t)sparse_features[b * 2 + 0] * NE + tid];
        pre_c = ctx_table[(size_t)sparse_features[b * 2 + 1] * NE + tid];
    } else if (tid < 80) {
        pre_d = dense_features[(size_t)b * 16 + (tid - 64)];
    }

    // ---- stage q, b2, wo -------------------------------------------------
    if (tid < NE) sm.q[tid] = item_table[(size_t)target_item[b] * NE + tid];
    if (tid < 32) { sm.b2[tid] = att_b2[tid]; sm.wo[tid] = att_wo[tid]; }
    const float bo = att_bo[0];
    __syncthreads();

    // ---- Weff^T split staging (1 b128 store/thread) + bias partials -----
    {
        const int j  = tid & 63;
        const int eb = (tid >> 6) * 8;   // 8 consecutive e per thread
        float pb = 0.f;
        bf16x8 vhi, vlo;
#pragma unroll
        for (int i = 0; i < 8; ++i) {
            const int e = eb + i;
            const float qe = sm.q[e];
            const float A  = att_w1[(size_t)(e)       * NE + j];
            const float Bv = att_w1[(size_t)(64 + e)  * NE + j];
            const float C  = att_w1[(size_t)(128 + e) * NE + j];
            const float D  = att_w1[(size_t)(192 + e) * NE + j];
            const float wf = A + C + qe * D;
            const __bf16 h = (__bf16)wf;
            vhi[i] = h;
            vlo[i] = (__bf16)(wf - (float)h);
            pb += qe * (Bv - C);
        }
        *(bf16x8*)(sm.wT_hi + (size_t)j * 72 + eb) = vhi;
        *(bf16x8*)(sm.wT_lo + (size_t)j * 72 + eb) = vlo;
        sm.ip[(tid >> 6) * 64 + j] = pb;
    }
    // w2T[o][j] split staging (b64 stores, 4 j per thread)
    {
        const int o  = tid & 31;
        const int jb = (tid >> 5) * 4;   // 0..60
        bf16x4 vhi, vlo;
#pragma unroll
        for (int i = 0; i < 4; ++i) {
            const float v = att_w2[(size_t)(jb + i) * 32 + o];
            const __bf16 h = (__bf16)v;
            vhi[i] = h;
            vlo[i] = (__bf16)(v - (float)h);
        }
        *(bf16x4*)(sm.w2T_hi + (size_t)o * 72 + jb) = vhi;
        *(bf16x4*)(sm.w2T_lo + (size_t)o * 72 + jb) = vlo;
    }
    __syncthreads();
    if (tid < NE) {
        float s = att_b1[tid];
#pragma unroll
        for (int w = 0; w < 8; ++w) s += sm.ip[w * 64 + tid];
        sm.biasj[tid] = s;
    }
    __syncthreads();

    // ---- L1 GEMM: h1 = K . Weff  (split-3, 48 MFMA/wave) ----------------
    f32x4 acc1[2][4];
    {
        const f32x4 z = {0.f, 0.f, 0.f, 0.f};
#pragma unroll
        for (int mt = 0; mt < 2; ++mt)
#pragma unroll
            for (int nt = 0; nt < 4; ++nt) acc1[mt][nt] = z;
    }
#pragma unroll
    for (int nt = 0; nt < 4; ++nt) {
        const __bf16* bph = sm.wT_hi + (nt * 16 + l15) * 72 + g4 * 8;
        const __bf16* bpl = sm.wT_lo + (nt * 16 + l15) * 72 + g4 * 8;
        const bf16x8 bh0 = *(const bf16x8*)(bph);
        const bf16x8 bh1 = *(const bf16x8*)(bph + 32);
        const bf16x8 bl0 = *(const bf16x8*)(bpl);
        const bf16x8 bl1 = *(const bf16x8*)(bpl + 32);
#pragma unroll
        for (int mt = 0; mt < 2; ++mt) {
            f32x4 a = acc1[mt][nt];
            a = __builtin_amdgcn_mfma_f32_16x16x32_bf16(khi[mt][0], bh0, a, 0, 0, 0);
            a = __builtin_amdgcn_mfma_f32_16x16x32_bf16(khi[mt][0], bl0, a, 0, 0, 0);
            a = __builtin_amdgcn_mfma_f32_16x16x32_bf16(klo[mt][0], bh0, a, 0, 0, 0);
            a = __builtin_amdgcn_mfma_f32_16x16x32_bf16(khi[mt][1], bh1, a, 0, 0, 0);
            a = __builtin_amdgcn_mfma_f32_16x16x32_bf16(khi[mt][1], bl1, a, 0, 0, 0);
            a = __builtin_amdgcn_mfma_f32_16x16x32_bf16(klo[mt][1], bh1, a, 0, 0, 0);
            acc1[mt][nt] = a;
        }
    }

    // ---- bias + ReLU on C1 (col = nt*16+l15, row-in-tile = g4*4+r) ------
#pragma unroll
    for (int nt = 0; nt < 4; ++nt) {
        const float bj = sm.biasj[nt * 16 + l15];
#pragma unroll
        for (int mt = 0; mt < 2; ++mt)
#pragma unroll
            for (int r = 0; r < 4; ++r)
                acc1[mt][nt][r] = fmaxf(acc1[mt][nt][r] + bj, 0.f);
    }

    // ---- transpose C1-layout -> A2-fragments via wave-private bounce ----
    bf16x8 a2hi[2][2], a2lo[2][2];
    {
        float* bnc = sm.bounce[wv];
#pragma unroll
        for (int mt = 0; mt < 2; ++mt) {
#pragma unroll
            for (int k2s = 0; k2s < 2; ++k2s) {
#pragma unroll
                for (int ntl = 0; ntl < 2; ++ntl) {
                    const int nt = k2s * 2 + ntl;
#pragma unroll
                    for (int r = 0; r < 4; ++r)
                        bnc[(g4 * 4 + r) * 36 + ntl * 16 + l15] = acc1[mt][nt][r];
                }
                // same-wave DS ops are ordered; compiler inserts lgkm waits
                const float* rp = bnc + l15 * 36 + g4 * 8;
                const float4 u0 = *(const float4*)(rp);
                const float4 u1 = *(const float4*)(rp + 4);
                cvt8(u0, u1, a2hi[mt][k2s], a2lo[mt][k2s]);
            }
        }
    }

    // ---- L2 GEMM: h2 = h1 . W2 (split-3, 24 MFMA/wave) ------------------
    f32x4 acc2[2][2];
    {
        const f32x4 z = {0.f, 0.f, 0.f, 0.f};
#pragma unroll
        for (int mt = 0; mt < 2; ++mt) { acc2[mt][0] = z; acc2[mt][1] = z; }
    }
#pragma unroll
    for (int nt2 = 0; nt2 < 2; ++nt2) {
        const __bf16* bph = sm.w2T_hi + (nt2 * 16 + l15) * 72 + g4 * 8;
        const __bf16* bpl = sm.w2T_lo + (nt2 * 16 + l15) * 72 + g4 * 8;
        const bf16x8 bh0 = *(const bf16x8*)(bph);
        const bf16x8 bh1 = *(const bf16x8*)(bph + 32);
        const bf16x8 bl0 = *(const bf16x8*)(bpl);
        const bf16x8 bl1 = *(const bf16x8*)(bpl + 32);
#pragma unroll
        for (int mt = 0; mt < 2; ++mt) {
            f32x4 a = acc2[mt][nt2];
            a = __builtin_amdgcn_mfma_f32_16x16x32_bf16(a2hi[mt][0], bh0, a, 0, 0, 0);
            a = __builtin_amdgcn_mfma_f32_16x16x32_bf16(a2hi[mt][0], bl0, a, 0, 0, 0);
            a = __builtin_amdgcn_mfma_f32_16x16x32_bf16(a2lo[mt][0], bh0, a, 0, 0, 0);
            a = __builtin_amdgcn_mfma_f32_16x16x32_bf16(a2hi[mt][1], bh1, a, 0, 0, 0);
            a = __builtin_amdgcn_mfma_f32_16x16x32_bf16(a2hi[mt][1], bl1, a, 0, 0, 0);
            a = __builtin_amdgcn_mfma_f32_16x16x32_bf16(a2lo[mt][1], bh1, a, 0, 0, 0);
            acc2[mt][nt2] = a;
        }
    }

    // ---- L3 scores: relu(h2+b2).wo, reduce over the 16 col-lanes --------
    float sc[2][4];
#pragma unroll
    for (int mt = 0; mt < 2; ++mt)
#pragma unroll
        for (int r = 0; r < 4; ++r) sc[mt][r] = 0.f;
#pragma unroll
    for (int nt2 = 0; nt2 < 2; ++nt2) {
        const float bb = sm.b2[nt2 * 16 + l15];
        const float ww = sm.wo[nt2 * 16 + l15];
#pragma unroll
        for (int mt = 0; mt < 2; ++mt)
#pragma unroll
            for (int r = 0; r < 4; ++r)
                sc[mt][r] += fmaxf(acc2[mt][nt2][r] + bb, 0.f) * ww;
    }
#pragma unroll
    for (int mt = 0; mt < 2; ++mt)
#pragma unroll
        for (int r = 0; r < 4; ++r) {
            float v = sc[mt][r];
            v += __shfl_xor(v, 1);
            v += __shfl_xor(v, 2);
            v += __shfl_xor(v, 4);
            v += __shfl_xor(v, 8);
            sc[mt][r] = v;
        }
    if (l15 == 0) {
#pragma unroll
        for (int mt = 0; mt < 2; ++mt)
#pragma unroll
            for (int r = 0; r < 4; ++r) {
                const int t = 32 * wv + mt * 16 + g4 * 4 + r;
                float val;
                if (t < NT) {
                    const int mk = history_mask[(size_t)b * NT + t];
                    val = (mk != 0) ? (sc[mt][r] + bo) : -1e9f;
                } else {
                    val = -INFINITY;       // pad rows excluded from softmax
                }
                sm.scores[t] = val;
            }
    }
    __syncthreads();

    // ---- softmax over 256 slots (8-wave reduce; tid>=256 inert) ---------
    const float v = (tid < 256) ? sm.scores[tid] : -INFINITY;
    float m = v;
#pragma unroll
    for (int s = 32; s; s >>= 1) m = fmaxf(m, __shfl_xor(m, s));
    if (lane == 0) sm.red_a[wv] = m;
    __syncthreads();
    float mx = sm.red_a[0];
#pragma unroll
    for (int w = 1; w < 8; ++w) mx = fmaxf(mx, sm.red_a[w]);
    const float ex = __expf(v - mx);   // -inf -> 0
    float ssum = ex;
#pragma unroll
    for (int s = 32; s; s >>= 1) ssum += __shfl_xor(ssum, s);
    if (lane == 0) sm.red_b[wv] = ssum;
    __syncthreads();
    float total = 0.f;
#pragma unroll
    for (int w = 0; w < 8; ++w) total += sm.red_b[w];
    if (tid < 256) sm.scores[tid] = ex / total;   // softmax weight of slot
    __syncthreads();

    // ---- interest in FP32: re-gather K rows (L2/L3-hot), 25 t per wave --
    {
        const int e = lane;            // 0..63
        float acc = 0.f;
        const int tb = 25 * wv;        // 8 waves x 25 = 200 exactly
#pragma unroll 5
        for (int i = 0; i < 25; ++i) {
            const int t = tb + i;
            const float wt = sm.scores[t];
            const int hr = history_items[(size_t)b * NT + t];
            acc += wt * item_table[(size_t)hr * NE + e];
        }
        sm.ip[wv * 64 + e] = acc;
    }
    __syncthreads();

    // ---- assemble mlp_in row [user, ctx, q, interest, dense] ------------
    float* row = mlp_in + (size_t)b * 272;
    if (tid < NE) {
        float inter = 0.f;
#pragma unroll
        for (int w = 0; w < 8; ++w) inter += sm.ip[w * 64 + tid];
        row[0 + tid]   = pre_u;
        row[64 + tid]  = pre_c;
        row[128 + tid] = sm.q[tid];
        row[192 + tid] = inter;
    } else if (tid >= 64 && tid < 80) {
        row[256 + (tid - 64)] = pre_d;
    }
}

// ---------------------------------------------------------------------------
// Kernel 2: final MLP 272 -> 256 -> 128 -> 1 via MFMA (split-3 bf16).
// Block = 16 batch rows, 512 threads (8 waves), grid 256 (1 block/CU).
// GEMM1: wave w covers cols [32w,32w+32): 2nt x 9ks x 3 = 54 MFMA.
// GEMM2: wave w covers cols [16w,16w+16): 8ks x 3 = 24 MFMA.
// GEMM3: shuffle-reduce dot with out_w.
// ---------------------------------------------------------------------------
#define XP 296   // LDS K-pitch: 148 dw = 20 mod 32 -> 2-way banks (free)

struct __align__(16) SmemL {
    __bf16 xh[16 * XP];    // X rows, bf16-hi, zero-padded k in [272,296)
    __bf16 xl[16 * XP];
    __bf16 h1h[16 * XP];   // h1 rows (k = n1 in [0,256))
    __bf16 h1l[16 * XP];
    float  b1v[256];
    float  b2v[128];
    float  owv[128];
    float  part[8][16];
};                          // ~40.4 KB

__global__ __launch_bounds__(512)
void din_mlp(const float* __restrict__ mlp_in,
             const float* __restrict__ w1,
             const float* __restrict__ b1,
             const float* __restrict__ w2,
             const float* __restrict__ b2,
             const float* __restrict__ ow,
             const float* __restrict__ ob,
             float* __restrict__ out)
{
    __shared__ SmemL sm;

    const int b0   = blockIdx.x * 16;
    const int tid  = threadIdx.x;    // 0..511
    const int wv   = tid >> 6;       // wave 0..7
    const int lane = tid & 63;
    const int l15  = lane & 15;
    const int g4   = lane >> 4;      // 0..3

    // ---- stage X rows as bf16 hi/lo, zero-padded to XP ------------------
    for (int i = tid; i < 16 * XP; i += 512) {
        const int r = i / XP, k = i - r * XP;
        const float v = (k < 272) ? mlp_in[(size_t)(b0 + r) * 272 + k] : 0.f;
        const __bf16 h = (__bf16)v;
        sm.xh[i] = h;
        sm.xl[i] = (__bf16)(v - (float)h);
    }
    if (tid < 256) sm.b1v[tid] = b1[tid];
    else if (tid < 384) sm.b2v[tid - 256] = b2[tid - 256];
    else sm.owv[tid - 384] = ow[tid - 384];
    __syncthreads();

    // ---- GEMM1: h1[16x256] = X[16x288] . W1  (54 MFMA/wave) -------------
    f32x4 acc[2];
    {
        const f32x4 z = {0.f, 0.f, 0.f, 0.f};
        acc[0] = z; acc[1] = z;
    }
#pragma unroll
    for (int ks = 0; ks < 9; ++ks) {
        const bf16x8 ah = *(const bf16x8*)(sm.xh + l15 * XP + ks * 32 + g4 * 8);
        const bf16x8 al = *(const bf16x8*)(sm.xl + l15 * XP + ks * 32 + g4 * 8);
#pragma unroll
        for (int nt = 0; nt < 2; ++nt) {
            const int n = wv * 32 + nt * 16 + l15;
            float wf[8];
            if (ks < 8) {
#pragma unroll
                for (int i = 0; i < 8; ++i)
                    wf[i] = w1[(size_t)(ks * 32 + g4 * 8 + i) * 256 + n];
            } else {
                // k in [256,288): valid only while k < 272 (g4*8+i < 16)
#pragma unroll
                for (int i = 0; i < 8; ++i) wf[i] = 0.f;
                if (g4 < 2) {
#pragma unroll
                    for (int i = 0; i < 8; ++i)
                        wf[i] = w1[(size_t)(256 + g4 * 8 + i) * 256 + n];
                }
            }
            bf16x8 bh, bl;
            cvt8a(wf, bh, bl);
            f32x4 a = acc[nt];
            a = __builtin_amdgcn_mfma_f32_16x16x32_bf16(ah, bh, a, 0, 0, 0);
            a = __builtin_amdgcn_mfma_f32_16x16x32_bf16(ah, bl, a, 0, 0, 0);
            a = __builtin_amdgcn_mfma_f32_16x16x32_bf16(al, bh, a, 0, 0, 0);
            acc[nt] = a;
        }
    }

    // ---- bias + relu, split, write h1 to LDS ----------------------------
#pragma unroll
    for (int nt = 0; nt < 2; ++nt) {
        const int n = wv * 32 + nt * 16 + l15;
        const float bias = sm.b1v[n];
#pragma unroll
        for (int r = 0; r < 4; ++r) {
            const float v = fmaxf(acc[nt][r] + bias, 0.f);
            const __bf16 h = (__bf16)v;
            sm.h1h[(g4 * 4 + r) * XP + n] = h;
            sm.h1l[(g4 * 4 + r) * XP + n] = (__bf16)(v - (float)h);
        }
    }
    __syncthreads();

    // ---- GEMM2: h2[16x128] = h1[16x256] . W2  (24 MFMA/wave) ------------
    f32x4 acc2;
    {
        const f32x4 z = {0.f, 0.f, 0.f, 0.f};
        acc2 = z;
    }
    const int n2 = wv * 16 + l15;
#pragma unroll
    for (int ks = 0; ks < 8; ++ks) {
        const bf16x8 ah = *(const bf16x8*)(sm.h1h + l15 * XP + ks * 32 + g4 * 8);
        const bf16x8 al = *(const bf16x8*)(sm.h1l + l15 * XP + ks * 32 + g4 * 8);
        float wf[8];
#pragma unroll
        for (int i = 0; i < 8; ++i)
            wf[i] = w2[(size_t)(ks * 32 + g4 * 8 + i) * 128 + n2];
        bf16x8 bh, bl;
        cvt8a(wf, bh, bl);
        acc2 = __builtin_amdgcn_mfma_f32_16x16x32_bf16(ah, bh, acc2, 0, 0, 0);
        acc2 = __builtin_amdgcn_mfma_f32_16x16x32_bf16(ah, bl, acc2, 0, 0, 0);
        acc2 = __builtin_amdgcn_mfma_f32_16x16x32_bf16(al, bh, acc2, 0, 0, 0);
    }

    // ---- GEMM3: out = relu(h2+b2) . ow + ob -----------------------------
    {
        const float bias = sm.b2v[n2];
        const float ww   = sm.owv[n2];
        float s[4];
#pragma unroll
        for (int r = 0; r < 4; ++r) {
            float v = fmaxf(acc2[r] + bias, 0.f) * ww;
            v += __shfl_xor(v, 1);
            v += __shfl_xor(v, 2);
            v += __shfl_xor(v, 4);
            v += __shfl_xor(v, 8);
            s[r] = v;
        }
        if (l15 == 0) {
#pragma unroll
            for (int r = 0; r < 4; ++r)
                sm.part[wv][g4 * 4 + r] = s[r];
        }
    }
    __syncthreads();
    if (tid < 16) {
        float o = ob[0];
#pragma unroll
        for (int w = 0; w < 8; ++w) o += sm.part[w][tid];
        out[b0 + tid] = o;
    }
}

// ---------------------------------------------------------------------------
extern "C" void kernel_launch(void* const* d_in, const int* in_sizes, int n_in,
                              void* d_out, int out_size, void* d_ws, size_t ws_size,
                              hipStream_t stream)
{
    float* mlp_in = (float*)d_ws;   // 4096*272*4 = 4.46 MB

    din_attn<<<NB, 512, 0, stream>>>(
        (const int*)d_in[0],      // target_item
        (const int*)d_in[1],      // history_items
        (const int*)d_in[2],      // history_mask
        (const int*)d_in[3],      // sparse_features
        (const float*)d_in[4],    // dense_features
        (const float*)d_in[5],    // item_table
        (const float*)d_in[6],    // user_table
        (const float*)d_in[7],    // ctx_table
        (const float*)d_in[8],  (const float*)d_in[9],   // att_w1, att_b1
        (const float*)d_in[10], (const float*)d_in[11],  // att_w2, att_b2
        (const float*)d_in[12], (const float*)d_in[13],  // att_wo, att_bo
        mlp_in);

    din_mlp<<<NB / 16, 512, 0, stream>>>(
        mlp_in,
        (const float*)d_in[14], (const float*)d_in[15],  // mlp_w1, mlp_b1
        (const float*)d_in[16], (const float*)d_in[17],  // mlp_w2, mlp_b2
        (const float*)d_in[18], (const float*)d_in[19],  // out_w, out_b
        (float*)d_out);
}